// Round 13
// baseline (523.764 us; speedup 1.0000x reference)
//
#include <hip/hip_runtime.h>
#include <hip/hip_bf16.h>
#include <stdint.h>

#define N_NODES 50000
#define N_EDGES 800000
#define NBG 196                  // ceil(50000/256) per-graph scan blocks
#define MG64 782                 // ceil(N_NODES/64) (gemm M=64 tiles)
#define EG4 782                  // ceil(800000/1024) 4-edge-per-thread blocks
#define G256S8 6256              // 8*782: gath<256> SPLIT=8 (64-row tiles, NL=1)
#define G128S4 3128              // 8*391: gath<128> SPLIT=4 (64-row tiles, NL=2)
#define AGG2G 3128               // agg2 SPLIT=4 grid (64-row tiles, NL=2)

typedef __attribute__((ext_vector_type(8))) short short8;
typedef __attribute__((ext_vector_type(4))) float floatx4;

__device__ __forceinline__ float bfbits2f(unsigned int u16) {
    union { unsigned int i; float f; } c; c.i = u16 << 16; return c.f;
}
__device__ __forceinline__ unsigned short f2bfbits(float f) {
    union { float f; unsigned int i; } c; c.f = f;
    unsigned int r = c.i + 0x7fffu + ((c.i >> 16) & 1u);   // RNE
    return (unsigned short)(r >> 16);
}
__device__ __forceinline__ void acc8(float* a, uint4 v) {
    a[0] += bfbits2f(v.x & 0xffffu); a[1] += bfbits2f(v.x >> 16);
    a[2] += bfbits2f(v.y & 0xffffu); a[3] += bfbits2f(v.y >> 16);
    a[4] += bfbits2f(v.z & 0xffffu); a[5] += bfbits2f(v.z >> 16);
    a[6] += bfbits2f(v.w & 0xffffu); a[7] += bfbits2f(v.w >> 16);
}

// 8-deep gather body — r7-proven. r8: 16-deep neutral. r9: fusion loses.
#define GATHER_RUN(IDX)                                                        \
    {                                                                          \
        int j = 0;                                                             \
        for (; j + 7 < deg; j += 8) {                                          \
            uint4 vv[8];                                                       \
            _Pragma("unroll")                                                  \
            for (int u = 0; u < 8; ++u)                                        \
                vv[u] = *(const uint4*)(col + (size_t)IDX(j + u) * K);         \
            _Pragma("unroll")                                                  \
            for (int u = 0; u < 8; ++u) acc8((u & 1) ? g : a, vv[u]);          \
        }                                                                      \
        for (; j + 1 < deg; j += 2) {                                          \
            uint4 v0 = *(const uint4*)(col + (size_t)IDX(j) * K);              \
            uint4 v1 = *(const uint4*)(col + (size_t)IDX(j + 1) * K);          \
            acc8(a, v0); acc8(g, v1);                                          \
        }                                                                      \
        if (j < deg) {                                                         \
            uint4 v0 = *(const uint4*)(col + (size_t)IDX(j) * K);              \
            acc8(a, v0);                                                       \
        }                                                                      \
    }

// 4-edge count. useRank: keep fetch-add return as the edge's rank -> fills
// become atomic-free (r6: fill fetch-adds cost 64B HBM RMW each).
__device__ __forceinline__ void count4_body(
    int blk, int tid, const int* __restrict__ e, int* __restrict__ rp,
    int* __restrict__ rank, int f1, int useRank)
{
#pragma unroll
    for (int u = 0; u < 4; ++u) {
        int i = blk * 1024 + u * 256 + tid;
        if (i < N_EDGES) {
            int dst = f1 ? e[2 * (N_EDGES + i)] : e[N_EDGES + i];
            if (useRank) rank[i] = atomicAdd(&rp[dst], 1);
            else         atomicAdd(&rp[dst], 1);
        }
    }
}

// 4-edge fill. useRank: atomic-free (pristine rp prefix + rank).
__device__ __forceinline__ void fill4_body(
    int blk, int tid, const int* __restrict__ e, int* __restrict__ rp,
    const int* __restrict__ part, int* __restrict__ csr,
    const int* __restrict__ rank, int f1, int useRank)
{
#pragma unroll
    for (int u = 0; u < 4; ++u) {
        int i = blk * 1024 + u * 256 + tid;
        if (i < N_EDGES) {
            int src = f1 ? e[2 * i] : e[i];
            int dst = f1 ? e[2 * (N_EDGES + i)] : e[N_EDGES + i];
            int pos;
            if (useRank) pos = part[dst >> 8] + rp[dst] + rank[i];
            else         pos = part[dst >> 8] + atomicAdd(&rp[dst], 1);
            csr[pos] = src;
        }
    }
}

// boundary loader: useRank -> pristine rp; legacy -> post-fill cursor at idx-1.
__device__ __forceinline__ int srp_load(
    int m0, int tid, const int* __restrict__ rp, const int* __restrict__ part,
    int useRank)
{
    int r0 = m0 + tid - (useRank ? 0 : 1);
    if (r0 < 0) return 0;
    if (r0 >= N_NODES) return N_EDGES;
    return rp[r0] + part[r0 >> 8];
}

// ---- mega1: count graph0 FRONT-LOADED + detect + weight/bias prep + x->bf16 ----
__global__ __launch_bounds__(256) void mega1(
    const void* __restrict__ Wl0, const void* __restrict__ Wr0,
    const void* __restrict__ Wl1, const void* __restrict__ Wr1,
    const void* __restrict__ Wl2, const void* __restrict__ Wr2,
    const void* __restrict__ b0, const void* __restrict__ b1, const void* __restrict__ b2,
    unsigned short* __restrict__ wt,
    const void* __restrict__ x, unsigned short* __restrict__ xb,
    const int* __restrict__ e0,
    int* __restrict__ rp0, int* __restrict__ rank, int useRank,
    int* __restrict__ flagsOut)
{
    __shared__ int s_cnt[2];
    const int t = threadIdx.x;
    if (t < 2) s_cnt[t] = 0;
    __syncthreads();
    {   // local detect (r2-verified logic; ballot-reduced)
        unsigned short v = ((const unsigned short*)x)[2 * t];
        int ex = (v >> 7) & 0xff;
        unsigned long long m0 = __ballot(v == 0 || (ex >= 96 && ex <= 150));
        unsigned long long m1 = __ballot(e0[2 * t + 1] != 0);
        if ((t & 63) == 0) {
            atomicAdd(&s_cnt[0], (int)__popcll(m0));
            atomicAdd(&s_cnt[1], (int)__popcll(m1));
        }
    }
    __syncthreads();
    const int f0 = (s_cnt[0] < 200) ? 1 : 0;
    const int f1 = (s_cnt[1] < 128) ? 1 : 0;
    const int bid = blockIdx.x;

    if (bid < 782) {                         // count0 FIRST: 782 blocks x 1024 edges
        count4_body(bid, t, e0, rp0, rank, f1, useRank);
        return;
    }
    if (bid == 8059) {
        if (t == 0) { flagsOut[0] = f0; flagsOut[1] = f1; }
        return;
    }
    if (bid >= 1809) {                       // cvt_x: 6250 blocks, 4 elems/thread
        int i = (bid - 1809) * 256 + t;
        if (f0) {
            float4 v = ((const float4*)x)[i];
            uint2 o;
            o.x = (unsigned int)f2bfbits(v.x) | ((unsigned int)f2bfbits(v.y) << 16);
            o.y = (unsigned int)f2bfbits(v.z) | ((unsigned int)f2bfbits(v.w) << 16);
            ((uint2*)xb)[i] = o;
        } else {
            ((uint2*)xb)[i] = ((const uint2*)x)[i];
        }
        return;
    }
    if (bid >= 1806) {                       // biases
        const void* bs = bid == 1806 ? b0 : (bid == 1807 ? b1 : b2);
        unsigned short* bd = wt + 262144 + (bid - 1806) * 256;
        int n = (bid == 1808) ? 128 : 256;
        if (t < n) bd[t] = f0 ? f2bfbits(((const float*)bs)[t]) : ((const unsigned short*)bs)[t];
        return;
    }
    // weights [782,1806): WcatT layout (L0/L1), stacked-N pair (L2)
    const int wb = bid - 782;
    const void* W; unsigned short* WT; int Nd, SK, KO, off;
    if (wb < 128)      { W = Wl0; WT = wt;          Nd = 256; off = wb;       SK = 256; KO = 0;   }
    else if (wb < 256) { W = Wr0; WT = wt;          Nd = 256; off = wb - 128; SK = 256; KO = 128; }
    else if (wb < 512) { W = Wl1; WT = wt + 65536;  Nd = 256; off = wb - 256; SK = 512; KO = 0;   }
    else if (wb < 768) { W = Wr1; WT = wt + 65536;  Nd = 256; off = wb - 512; SK = 512; KO = 256; }
    else if (wb < 896) { W = Wl2; WT = wt + 196608; Nd = 128; off = wb - 768; SK = 256; KO = 0;   }
    else               { W = Wr2; WT = wt + 229376; Nd = 128; off = wb - 896; SK = 256; KO = 0;   }
    int idx = off * 256 + t;
    int k = idx / Nd, n = idx - k * Nd;
    unsigned short v = f0 ? f2bfbits(((const float*)W)[idx]) : ((const unsigned short*)W)[idx];
    WT[n * SK + KO + k] = v;
}

// ---- scan_g: per-graph two-level exclusive scan (proven ticket pattern) ----
__global__ __launch_bounds__(256) void scan_g(
    int* __restrict__ rp, int* __restrict__ part, int* __restrict__ ticket)
{
    __shared__ int sa[256], sb[256];
    __shared__ int lastBlk;
    const int b = blockIdx.x, t = threadIdx.x, idx = b * 256 + t;
    int v = (idx < N_NODES) ? rp[idx] : 0;
    sa[t] = v;
    __syncthreads();
    bool par = true;
#pragma unroll
    for (int off = 1; off < 256; off <<= 1) {
        if (par) { int x2 = sa[t] + (t >= off ? sa[t - off] : 0); sb[t] = x2; }
        else     { int x2 = sb[t] + (t >= off ? sb[t - off] : 0); sa[t] = x2; }
        par = !par;
        __syncthreads();
    }
    if (idx < N_NODES) rp[idx] = sa[t] - v;          // local exclusive
    if (t == 255) part[b] = sa[255];
    __threadfence();                                  // publish before ticket
    if (t == 0) lastBlk = (atomicAdd(ticket, 1) == (int)gridDim.x - 1) ? 1 : 0;
    __syncthreads();
    if (!lastBlk) return;

    // exclusive scan of part[0..NBG) — fits one 256-wide pass
    int pv = (t < NBG) ? atomicAdd(&part[t], 0) : 0;  // coherent read
    sa[t] = pv;
    __syncthreads();
    par = true;
#pragma unroll
    for (int off = 1; off < 256; off <<= 1) {
        if (par) { int x2 = sa[t] + (t >= off ? sa[t - off] : 0); sb[t] = x2; }
        else     { int x2 = sb[t] + (t >= off ? sb[t - off] : 0); sa[t] = x2; }
        par = !par;
        __syncthreads();
    }
    if (t < NBG) part[t] = sa[t] - pv;               // global exclusive
}

__global__ __launch_bounds__(256) void fill_k(
    const int* __restrict__ e, int* __restrict__ rp, const int* __restrict__ part,
    int* __restrict__ csr, const int* __restrict__ rank, int useRank,
    const int* __restrict__ flags)
{
    fill4_body(blockIdx.x, threadIdx.x, e, rp, part, csr, rank, flags[1], useRank);
}

// ---- gath: gather+mean. Front blocks: count rider. SPLIT=S: each block owns
//      one COLUMN 1/S-slice, slice constant per XCD under blockIdx%8 RR ->
//      per-XCD L2 working set = 25.6MB/S. r11/r12 dose-response: SPLIT=2 gave
//      FETCH 175->149MB, dur 87->78. Now split to CACHE FIT: 3.2MB/XCD < 4MB
//      L2 (SPLIT=8 @K=256, SPLIT=4 @K=128); per-row read = 64B = 1 line.
template<int K, int OSTR, int ROWS, int SPLIT>
__global__ __launch_bounds__(256) void gath(
    const unsigned short* __restrict__ hin,   // [N,K] bf16 (stride K)
    const int* __restrict__ rp, const int* __restrict__ part,
    const int* __restrict__ csr_src,
    unsigned short* __restrict__ mout,
    const int* __restrict__ eN, int* __restrict__ rpN,
    int* __restrict__ rankN, int useRank,
    const int* __restrict__ flags)
{
    constexpr int CH = K / 8;                 // 8-col chunks per row
    constexpr int CHS = CH / SPLIT;           // chunks this block owns
    static_assert(ROWS * CHS == 256, "one work item per thread");
    constexpr int NL = 8 / SPLIT;             // grid lanes per col-slice
    constexpr int CAP = 64 * ROWS;            // sidx capacity (4x mean degree)
    constexpr int NT = (N_NODES + ROWS - 1) / ROWS;
    __shared__ int sidx[CAP];
    __shared__ int srp[ROWS + 1];
    const int tid = threadIdx.x;
    if (blockIdx.x < EG4) {                   // count rider (front-loaded)
        count4_body(blockIdx.x, tid, eN, rpN, rankN, flags[1], useRank);
        return;
    }
    const int gb = (int)blockIdx.x - EG4;
    int m0, chBase;
    if (SPLIT == 1) {
        m0 = gb * ROWS; chBase = 0;
    } else {
        const int q = gb >> 3, r = gb & 7;
        const int tile = q * NL + (r & (NL - 1));
        if (tile >= NT) return;
        m0 = tile * ROWS;
        chBase = (r / NL) * CHS;              // XCD-affine under %8 RR
    }
    if (tid < ROWS + 1) srp[tid] = srp_load(m0, tid, rp, part, useRank);
    __syncthreads();
    const int base = srp[0];
    const int total = srp[ROWS] - base;
    const bool staged = total <= CAP;
    if (staged) {
        for (int i = tid; i < total; i += 256) sidx[i] = csr_src[base + i];
    }
    __syncthreads();

    {
        const int rr = tid / CHS;
        const int cc = tid & (CHS - 1);
        const int beg = srp[rr];
        const int deg = srp[rr + 1] - beg;
        const int begl = beg - base;
        float a[8], g[8];
#pragma unroll
        for (int v = 0; v < 8; ++v) { a[v] = 0.f; g[v] = 0.f; }
        const unsigned short* col = hin + (chBase + cc) * 8;
        if (staged) {
            auto IDX = [&](int j) { return sidx[begl + j]; };
            GATHER_RUN(IDX)
        } else {
            auto IDX = [&](int j) { return csr_src[beg + j]; };
            GATHER_RUN(IDX)
        }
        const float inv = 1.0f / fmaxf((float)deg, 1.0f);
        short8 t8;
#pragma unroll
        for (int v = 0; v < 8; ++v) t8[v] = (short)f2bfbits((a[v] + g[v]) * inv);
        if (m0 + rr < N_NODES)
            *(short8*)(mout + (size_t)(m0 + rr) * OSTR + (chBase + cc) * 8) = t8;
    }
}

// ---- gemmcat: M=64 GEMM over concat A=[mean|self], WcatT[n][2K]; fill rider FIRST ----
template<int K>
__global__ __launch_bounds__(256) void gemmcat(
    const unsigned short* __restrict__ mean, int mstr,
    const unsigned short* __restrict__ self, int sstr,
    const unsigned short* __restrict__ WcatT, // [256][2K]
    const unsigned short* __restrict__ bb,
    unsigned short* __restrict__ hout,        // [N,256]
    const int* __restrict__ ef, int* __restrict__ rpf, const int* __restrict__ partf,
    int* __restrict__ csr, const int* __restrict__ rank, int useRank,
    const int* __restrict__ flags)
{
    constexpr int KE = 2 * K;
    constexpr int KH = 128;                   // staged K-slice
    constexpr int NKH = KE / KH;              // 2 (K=128) or 4 (K=256)
    constexpr int LDA = KH + 8;
    __shared__ unsigned short A[64][LDA];     // 17.4 KB
    const int tid = threadIdx.x;
    if (blockIdx.x < EG4) {                   // fill rider (front-loaded, atomic-free)
        fill4_body(blockIdx.x, tid, ef, rpf, partf, csr, rank, flags[1], useRank);
        return;
    }
    const int m0 = (blockIdx.x - EG4) * 64;
    const int lane = tid & 63, wave = tid >> 6;
    const int r = lane & 15, quad = lane >> 4;

    floatx4 acc[4][4] = {};                   // [nti][mt], static-indexed only

#pragma unroll
    for (int kh = 0; kh < NKH; ++kh) {
        if (kh) __syncthreads();              // LDS reuse: readers of prev slice done
        for (int i = tid; i < 64 * (KH / 8); i += 256) {
            const int row = i / (KH / 8);
            const int c8 = i - row * (KH / 8);
            int grow = m0 + row; if (grow >= N_NODES) grow = N_NODES - 1;
            const int gc = kh * KH + c8 * 8;  // concat column
            const unsigned short* src = (gc < K)
                ? (mean + (size_t)grow * mstr + gc)
                : (self + (size_t)grow * sstr + (gc - K));
            *(uint4*)&A[row][c8 * 8] = *(const uint4*)src;
        }
        __syncthreads();
#pragma unroll
        for (int nti = 0; nti < 4; ++nti) {
            const int n0 = (wave + nti * 4) * 16;
            short8 bf[KH / 32];               // 4 x 16B weight frags
            const unsigned short* bp = WcatT + (size_t)(n0 + r) * KE + kh * KH + quad * 8;
#pragma unroll
            for (int k0 = 0; k0 < KH / 32; ++k0) bf[k0] = *(const short8*)(bp + k0 * 32);
#pragma unroll
            for (int mt = 0; mt < 4; ++mt) {
#pragma unroll
                for (int k0 = 0; k0 < KH / 32; ++k0)
                    acc[nti][mt] = __builtin_amdgcn_mfma_f32_16x16x32_bf16(
                        *(const short8*)&A[mt * 16 + r][k0 * 32 + quad * 8],
                        bf[k0], acc[nti][mt], 0, 0, 0);
            }
        }
    }

    // epilogue: C/D layout col = lane&15, row = quad*4 + reg  [HW-verified]
#pragma unroll
    for (int nti = 0; nti < 4; ++nti) {
        const int ccol = (wave + nti * 4) * 16 + r;
        const float bv = bfbits2f(bb[ccol]);
#pragma unroll
        for (int mt = 0; mt < 4; ++mt) {
#pragma unroll
            for (int i = 0; i < 4; ++i) {
                const int row = m0 + mt * 16 + quad * 4 + i;
                float v = acc[nti][mt][i] + bv;
                v = v > 0.f ? v : 0.f;
                if (row < N_NODES) hout[(size_t)row * 256 + ccol] = f2bfbits(v);
            }
        }
    }
}

// ---- L2 GEMM pair (stacked-N weights), M=64, no rider ----
__global__ __launch_bounds__(256) void gemmL2(
    const unsigned short* __restrict__ A,
    const unsigned short* __restrict__ WT,    // stacked-N [256][256]
    unsigned short* __restrict__ out0,
    unsigned short* __restrict__ out1)
{
    __shared__ unsigned short As[64][264];
    const int tid = threadIdx.x;
    const int m0 = blockIdx.x * 64;
    for (int i = tid; i < 64 * 32; i += 256) {
        int rr = i >> 5, cc = i & 31;
        int row = m0 + rr; if (row >= N_NODES) row = N_NODES - 1;
        *(uint4*)&As[rr][cc * 8] = *(const uint4*)(A + (size_t)row * 256 + cc * 8);
    }
    __syncthreads();
    const int lane = tid & 63, wave = tid >> 6;
    const int r = lane & 15, quad = lane >> 4;

    for (int nt = wave; nt < 16; nt += 4) {
        const int n0 = nt * 16;
        short8 bf[8];
        const unsigned short* bp = WT + (size_t)(n0 + r) * 256 + quad * 8;
#pragma unroll
        for (int k0 = 0; k0 < 8; ++k0) bf[k0] = *(const short8*)(bp + k0 * 32);
        const int ccol = n0 + r;
#pragma unroll
        for (int mt = 0; mt < 4; ++mt) {
            floatx4 acc = {0.f, 0.f, 0.f, 0.f};
#pragma unroll
            for (int k0 = 0; k0 < 8; ++k0)
                acc = __builtin_amdgcn_mfma_f32_16x16x32_bf16(
                    *(const short8*)&As[mt * 16 + r][k0 * 32 + quad * 8], bf[k0], acc, 0, 0, 0);
#pragma unroll
            for (int i = 0; i < 4; ++i) {
                const int row = m0 + mt * 16 + quad * 4 + i;
                if (row < N_NODES) {
                    unsigned short v = f2bfbits(acc[i]);
                    if (ccol < 128) out0[(size_t)row * 128 + ccol] = v;
                    else            out1[(size_t)row * 128 + ccol - 128] = v;
                }
            }
        }
    }
}

// ---- L2 aggregate + epilogue, SPLIT=4 (64 rows x 4 chunks x 4 XCD-affine
//      quarters; 3.2MB/XCD fits L2 — same mechanism as gath) ----
__global__ __launch_bounds__(256) void agg2(
    const unsigned short* __restrict__ hl2,
    const unsigned short* __restrict__ hr2,
    const int* __restrict__ rp, const int* __restrict__ part,
    const int* __restrict__ csr_src,
    const unsigned short* __restrict__ bb,
    void* __restrict__ out, int useRank,
    const int* __restrict__ flags)
{
    constexpr int K = 128;
    constexpr int ROWS = 64, CHS = 4;         // 64*4 = 256 work items
    constexpr int CAP = 64 * ROWS;            // 4096
    constexpr int NT = (N_NODES + ROWS - 1) / ROWS;   // 782
    __shared__ int sidx[CAP];
    __shared__ int srp[ROWS + 1];
    const int tid = threadIdx.x;
    const int gb = blockIdx.x;
    const int q = gb >> 3, r8 = gb & 7;       // NL=2 lanes per quarter
    const int tile = q * 2 + (r8 & 1);
    if (tile >= NT) return;
    const int m0 = tile * ROWS;
    const int chBase = (r8 >> 1) * CHS;
    if (tid < ROWS + 1) srp[tid] = srp_load(m0, tid, rp, part, useRank);
    __syncthreads();
    const int base = srp[0];
    const int total = srp[ROWS] - base;
    const bool staged = total <= CAP;
    if (staged) {
        for (int i = tid; i < total; i += 256) sidx[i] = csr_src[base + i];
    }
    __syncthreads();

    const int rr = tid >> 2;                  // 0..63
    const int cc = tid & 3;                   // 0..3
    const int beg = srp[rr];
    const int deg = srp[rr + 1] - beg;
    const int begl = beg - base;
    float a[8], g[8];
#pragma unroll
    for (int v = 0; v < 8; ++v) { a[v] = 0.f; g[v] = 0.f; }
    const unsigned short* col = hl2 + (chBase + cc) * 8;
    if (staged) {
        auto IDX = [&](int j) { return sidx[begl + j]; };
        GATHER_RUN(IDX)
    } else {
        auto IDX = [&](int j) { return csr_src[beg + j]; };
        GATHER_RUN(IDX)
    }

    const float inv = 1.0f / fmaxf((float)deg, 1.0f);
    const int row = m0 + rr;
    const int rowc = (row < N_NODES) ? row : N_NODES - 1;
    const size_t ro = (size_t)rowc * K + (chBase + cc) * 8;
    uint4 hv = *(const uint4*)(hr2 + ro);
    uint4 bv = *(const uint4*)(bb + (chBase + cc) * 8);
    float h8[8], b8[8];
    h8[0] = bfbits2f(hv.x & 0xffffu); h8[1] = bfbits2f(hv.x >> 16);
    h8[2] = bfbits2f(hv.y & 0xffffu); h8[3] = bfbits2f(hv.y >> 16);
    h8[4] = bfbits2f(hv.z & 0xffffu); h8[5] = bfbits2f(hv.z >> 16);
    h8[6] = bfbits2f(hv.w & 0xffffu); h8[7] = bfbits2f(hv.w >> 16);
    b8[0] = bfbits2f(bv.x & 0xffffu); b8[1] = bfbits2f(bv.x >> 16);
    b8[2] = bfbits2f(bv.y & 0xffffu); b8[3] = bfbits2f(bv.y >> 16);
    b8[4] = bfbits2f(bv.z & 0xffffu); b8[5] = bfbits2f(bv.z >> 16);
    b8[6] = bfbits2f(bv.w & 0xffffu); b8[7] = bfbits2f(bv.w >> 16);
    float o8[8];
#pragma unroll
    for (int v = 0; v < 8; ++v) {
        float m = (a[v] + g[v]) * inv + b8[v] + h8[v];
        o8[v] = m > 0.f ? m : 0.f;
    }
    if (row >= N_NODES) return;
    if (flags[0]) {
        float* op = (float*)out + ro;
        float4 o0 = { o8[0], o8[1], o8[2], o8[3] };
        float4 o1 = { o8[4], o8[5], o8[6], o8[7] };
        *(float4*)op = o0;
        *(float4*)(op + 4) = o1;
    } else {
        short8 t8;
#pragma unroll
        for (int v = 0; v < 8; ++v) t8[v] = (short)f2bfbits(o8[v]);
        *(short8*)((unsigned short*)out + ro) = t8;
    }
}

// ---------------- orchestration ----------------
extern "C" void kernel_launch(void* const* d_in, const int* in_sizes, int n_in,
                              void* d_out, int out_size, void* d_ws, size_t ws_size,
                              hipStream_t stream) {
    const void* x  = d_in[0];
    const int* e[3] = { (const int*)d_in[1], (const int*)d_in[2], (const int*)d_in[3] };

    char* ws = (char*)d_ws;
    int* flags = (int*)ws;                                    // @0
    unsigned short* wt = (unsigned short*)(ws + 1024);        // 525,568 B -> 526,592
    unsigned short* bb0 = wt + 262144;
    unsigned short* bb1 = wt + 262400;
    unsigned short* bb2 = wt + 262656;
    int* rp3    = (int*)(ws + 526592);                        // 150,000 ints -> 1,126,592
    int* ticket = (int*)(ws + 1126592);                       // 3 ints -> 1,126,604
    int* part3  = (int*)(ws + 1126604);                       // 3*196 ints -> 1,128,956
    int* csr    = (int*)(ws + 1128960);                       // 3.2 MB -> 4,328,960
    unsigned short* hA = (unsigned short*)(ws + 4328960);     // 25.6 MB -> 29,928,960
    unsigned short* hB = (unsigned short*)(ws + 29928960);    // 25.6 MB -> 55,528,960
    int* rank  = (int*)(ws + 55528960);                       // 3.2 MB -> 58,728,960 (guarded)
    unsigned short* xb  = hB;                 // overlay: dies when gath1 writes hB (xb dead after gemm0)
    unsigned short* hl2 = hA;                 // overlay: hA dead after gemm1 reads it (self)
    unsigned short* hr2 = hA + (size_t)N_NODES * 128;

    const int useRank = (ws_size >= (size_t)58728960) ? 1 : 0;  // fallback = legacy cursor fill

    int* rp0 = rp3, * rp1 = rp3 + N_NODES, * rp2 = rp3 + 2 * N_NODES;
    int* pt0 = part3, * pt1 = part3 + NBG, * pt2 = part3 + 2 * NBG;

    // 1) zero counters + tickets (contiguous)
    hipMemsetAsync(rp3, 0, 600012, stream);
    // 2) prep + cvt + count graph0 (count0 FRONT-LOADED; writes rank when useRank)
    mega1<<<8060, 256, 0, stream>>>(d_in[4], d_in[6], d_in[7], d_in[9],
                                    d_in[10], d_in[12], d_in[5], d_in[8], d_in[11],
                                    wt, x, xb, e[0], rp0, rank, useRank, flags);
    // 3) scan graph0
    scan_g<<<NBG, 256, 0, stream>>>(rp0, pt0, ticket + 0);
    // 4) fill graph0 (atomic-free when useRank)
    fill_k<<<EG4, 256, 0, stream>>>(e[0], rp0, pt0, csr, rank, useRank, flags);
    // 5) gather0 SPLIT=4 (64-row tiles, 3.2MB/XCD): mean(xb) -> hA; rider: count graph1
    gath<128, 256, 64, 4><<<EG4 + G128S4, 256, 0, stream>>>(xb, rp0, pt0, csr, hA,
                                                            e[1], rp1, rank, useRank, flags);
    // 6) scan graph1 (tiny)
    scan_g<<<NBG, 256, 0, stream>>>(rp1, pt1, ticket + 1);
    // 7) L0 GEMM in-place on hA; front rider: fill graph1 (csr free after gath0)
    gemmcat<128><<<EG4 + MG64, 256, 0, stream>>>(hA, 256, xb, 128,
                                                 wt, bb0, hA,
                                                 e[1], rp1, pt1, csr, rank, useRank, flags);
    // 8) gather1 SPLIT=8 (64-row tiles, 3.2MB/XCD): mean(hA) -> hB; rider: count graph2
    gath<256, 256, 64, 8><<<EG4 + G256S8, 256, 0, stream>>>(hA, rp1, pt1, csr, hB,
                                                            e[2], rp2, rank, useRank, flags);
    // 9) scan graph2 (tiny)
    scan_g<<<NBG, 256, 0, stream>>>(rp2, pt2, ticket + 2);
    // 10) L1 GEMM in-place on hB (mean=hB, self=hA); front rider: fill graph2
    gemmcat<256><<<EG4 + MG64, 256, 0, stream>>>(hB, 256, hA, 256,
                                                 wt + 65536, bb1, hB,
                                                 e[2], rp2, pt2, csr, rank, useRank, flags);
    // 11) L2 GEMM pair (M=64)
    gemmL2<<<MG64, 256, 0, stream>>>(hB, wt + 196608, hl2, hr2);
    // 12) L2 aggregate + epilogue SPLIT=4 -> d_out
    agg2<<<AGG2G, 256, 0, stream>>>(hl2, hr2, rp2, pt2, csr, bb2, d_out, useRank, flags);
}

// Round 14
// 482.782 us; speedup vs baseline: 1.0849x; 1.0849x over previous
//
#include <hip/hip_runtime.h>
#include <hip/hip_bf16.h>
#include <stdint.h>

#define N_NODES 50000
#define N_EDGES 800000
#define NBG 196                  // ceil(50000/256) per-graph scan blocks
#define MG64 782                 // ceil(N_NODES/64) (gemm M=64 tiles)
#define EG4 782                  // ceil(800000/1024) 4-edge-per-thread blocks
#define G256S4 6256              // 8*782: gath<256> SPLIT=4 (32-row tiles, NL=2)
#define G128S2 3128              // 8*391: gath<128> SPLIT=2 (32-row tiles, NL=4)
#define AGG2G 3128               // agg2 SPLIT=2 grid (32-row tiles, NL=4)

typedef __attribute__((ext_vector_type(8))) short short8;
typedef __attribute__((ext_vector_type(4))) float floatx4;

__device__ __forceinline__ float bfbits2f(unsigned int u16) {
    union { unsigned int i; float f; } c; c.i = u16 << 16; return c.f;
}
__device__ __forceinline__ unsigned short f2bfbits(float f) {
    union { float f; unsigned int i; } c; c.f = f;
    unsigned int r = c.i + 0x7fffu + ((c.i >> 16) & 1u);   // RNE
    return (unsigned short)(r >> 16);
}
__device__ __forceinline__ void acc8(float* a, uint4 v) {
    a[0] += bfbits2f(v.x & 0xffffu); a[1] += bfbits2f(v.x >> 16);
    a[2] += bfbits2f(v.y & 0xffffu); a[3] += bfbits2f(v.y >> 16);
    a[4] += bfbits2f(v.z & 0xffffu); a[5] += bfbits2f(v.z >> 16);
    a[6] += bfbits2f(v.w & 0xffffu); a[7] += bfbits2f(v.w >> 16);
}

// 8-deep gather body — r7-proven. r8: 16-deep neutral. r9: fusion loses.
#define GATHER_RUN(IDX)                                                        \
    {                                                                          \
        int j = 0;                                                             \
        for (; j + 7 < deg; j += 8) {                                          \
            uint4 vv[8];                                                       \
            _Pragma("unroll")                                                  \
            for (int u = 0; u < 8; ++u)                                        \
                vv[u] = *(const uint4*)(col + (size_t)IDX(j + u) * K);         \
            _Pragma("unroll")                                                  \
            for (int u = 0; u < 8; ++u) acc8((u & 1) ? g : a, vv[u]);          \
        }                                                                      \
        for (; j + 1 < deg; j += 2) {                                          \
            uint4 v0 = *(const uint4*)(col + (size_t)IDX(j) * K);              \
            uint4 v1 = *(const uint4*)(col + (size_t)IDX(j + 1) * K);          \
            acc8(a, v0); acc8(g, v1);                                          \
        }                                                                      \
        if (j < deg) {                                                         \
            uint4 v0 = *(const uint4*)(col + (size_t)IDX(j) * K);              \
            acc8(a, v0);                                                       \
        }                                                                      \
    }

// 4-edge count. useRank: keep fetch-add return as the edge's rank -> fills
// become atomic-free (r6: fill fetch-adds cost 64B HBM RMW each).
__device__ __forceinline__ void count4_body(
    int blk, int tid, const int* __restrict__ e, int* __restrict__ rp,
    int* __restrict__ rank, int f1, int useRank)
{
#pragma unroll
    for (int u = 0; u < 4; ++u) {
        int i = blk * 1024 + u * 256 + tid;
        if (i < N_EDGES) {
            int dst = f1 ? e[2 * (N_EDGES + i)] : e[N_EDGES + i];
            if (useRank) rank[i] = atomicAdd(&rp[dst], 1);
            else         atomicAdd(&rp[dst], 1);
        }
    }
}

// 4-edge fill. useRank: atomic-free (pristine rp prefix + rank).
__device__ __forceinline__ void fill4_body(
    int blk, int tid, const int* __restrict__ e, int* __restrict__ rp,
    const int* __restrict__ part, int* __restrict__ csr,
    const int* __restrict__ rank, int f1, int useRank)
{
#pragma unroll
    for (int u = 0; u < 4; ++u) {
        int i = blk * 1024 + u * 256 + tid;
        if (i < N_EDGES) {
            int src = f1 ? e[2 * i] : e[i];
            int dst = f1 ? e[2 * (N_EDGES + i)] : e[N_EDGES + i];
            int pos;
            if (useRank) pos = part[dst >> 8] + rp[dst] + rank[i];
            else         pos = part[dst >> 8] + atomicAdd(&rp[dst], 1);
            csr[pos] = src;
        }
    }
}

// boundary loader: useRank -> pristine rp; legacy -> post-fill cursor at idx-1.
__device__ __forceinline__ int srp_load(
    int m0, int tid, const int* __restrict__ rp, const int* __restrict__ part,
    int useRank)
{
    int r0 = m0 + tid - (useRank ? 0 : 1);
    if (r0 < 0) return 0;
    if (r0 >= N_NODES) return N_EDGES;
    return rp[r0] + part[r0 >> 8];
}

// ---- mega1: count graph0 FRONT-LOADED + detect + weight/bias prep + x->bf16 ----
__global__ __launch_bounds__(256) void mega1(
    const void* __restrict__ Wl0, const void* __restrict__ Wr0,
    const void* __restrict__ Wl1, const void* __restrict__ Wr1,
    const void* __restrict__ Wl2, const void* __restrict__ Wr2,
    const void* __restrict__ b0, const void* __restrict__ b1, const void* __restrict__ b2,
    unsigned short* __restrict__ wt,
    const void* __restrict__ x, unsigned short* __restrict__ xb,
    const int* __restrict__ e0,
    int* __restrict__ rp0, int* __restrict__ rank, int useRank,
    int* __restrict__ flagsOut)
{
    __shared__ int s_cnt[2];
    const int t = threadIdx.x;
    if (t < 2) s_cnt[t] = 0;
    __syncthreads();
    {   // local detect (r2-verified logic; ballot-reduced)
        unsigned short v = ((const unsigned short*)x)[2 * t];
        int ex = (v >> 7) & 0xff;
        unsigned long long m0 = __ballot(v == 0 || (ex >= 96 && ex <= 150));
        unsigned long long m1 = __ballot(e0[2 * t + 1] != 0);
        if ((t & 63) == 0) {
            atomicAdd(&s_cnt[0], (int)__popcll(m0));
            atomicAdd(&s_cnt[1], (int)__popcll(m1));
        }
    }
    __syncthreads();
    const int f0 = (s_cnt[0] < 200) ? 1 : 0;
    const int f1 = (s_cnt[1] < 128) ? 1 : 0;
    const int bid = blockIdx.x;

    if (bid < 782) {                         // count0 FIRST: 782 blocks x 1024 edges
        count4_body(bid, t, e0, rp0, rank, f1, useRank);
        return;
    }
    if (bid == 8059) {
        if (t == 0) { flagsOut[0] = f0; flagsOut[1] = f1; }
        return;
    }
    if (bid >= 1809) {                       // cvt_x: 6250 blocks, 4 elems/thread
        int i = (bid - 1809) * 256 + t;
        if (f0) {
            float4 v = ((const float4*)x)[i];
            uint2 o;
            o.x = (unsigned int)f2bfbits(v.x) | ((unsigned int)f2bfbits(v.y) << 16);
            o.y = (unsigned int)f2bfbits(v.z) | ((unsigned int)f2bfbits(v.w) << 16);
            ((uint2*)xb)[i] = o;
        } else {
            ((uint2*)xb)[i] = ((const uint2*)x)[i];
        }
        return;
    }
    if (bid >= 1806) {                       // biases
        const void* bs = bid == 1806 ? b0 : (bid == 1807 ? b1 : b2);
        unsigned short* bd = wt + 262144 + (bid - 1806) * 256;
        int n = (bid == 1808) ? 128 : 256;
        if (t < n) bd[t] = f0 ? f2bfbits(((const float*)bs)[t]) : ((const unsigned short*)bs)[t];
        return;
    }
    // weights [782,1806): WcatT layout (L0/L1), stacked-N pair (L2)
    const int wb = bid - 782;
    const void* W; unsigned short* WT; int Nd, SK, KO, off;
    if (wb < 128)      { W = Wl0; WT = wt;          Nd = 256; off = wb;       SK = 256; KO = 0;   }
    else if (wb < 256) { W = Wr0; WT = wt;          Nd = 256; off = wb - 128; SK = 256; KO = 128; }
    else if (wb < 512) { W = Wl1; WT = wt + 65536;  Nd = 256; off = wb - 256; SK = 512; KO = 0;   }
    else if (wb < 768) { W = Wr1; WT = wt + 65536;  Nd = 256; off = wb - 512; SK = 512; KO = 256; }
    else if (wb < 896) { W = Wl2; WT = wt + 196608; Nd = 128; off = wb - 768; SK = 256; KO = 0;   }
    else               { W = Wr2; WT = wt + 229376; Nd = 128; off = wb - 896; SK = 256; KO = 0;   }
    int idx = off * 256 + t;
    int k = idx / Nd, n = idx - k * Nd;
    unsigned short v = f0 ? f2bfbits(((const float*)W)[idx]) : ((const unsigned short*)W)[idx];
    WT[n * SK + KO + k] = v;
}

// ---- scan_g: per-graph two-level exclusive scan (proven ticket pattern) ----
__global__ __launch_bounds__(256) void scan_g(
    int* __restrict__ rp, int* __restrict__ part, int* __restrict__ ticket)
{
    __shared__ int sa[256], sb[256];
    __shared__ int lastBlk;
    const int b = blockIdx.x, t = threadIdx.x, idx = b * 256 + t;
    int v = (idx < N_NODES) ? rp[idx] : 0;
    sa[t] = v;
    __syncthreads();
    bool par = true;
#pragma unroll
    for (int off = 1; off < 256; off <<= 1) {
        if (par) { int x2 = sa[t] + (t >= off ? sa[t - off] : 0); sb[t] = x2; }
        else     { int x2 = sb[t] + (t >= off ? sb[t - off] : 0); sa[t] = x2; }
        par = !par;
        __syncthreads();
    }
    if (idx < N_NODES) rp[idx] = sa[t] - v;          // local exclusive
    if (t == 255) part[b] = sa[255];
    __threadfence();                                  // publish before ticket
    if (t == 0) lastBlk = (atomicAdd(ticket, 1) == (int)gridDim.x - 1) ? 1 : 0;
    __syncthreads();
    if (!lastBlk) return;

    // exclusive scan of part[0..NBG) — fits one 256-wide pass
    int pv = (t < NBG) ? atomicAdd(&part[t], 0) : 0;  // coherent read
    sa[t] = pv;
    __syncthreads();
    par = true;
#pragma unroll
    for (int off = 1; off < 256; off <<= 1) {
        if (par) { int x2 = sa[t] + (t >= off ? sa[t - off] : 0); sb[t] = x2; }
        else     { int x2 = sb[t] + (t >= off ? sb[t - off] : 0); sa[t] = x2; }
        par = !par;
        __syncthreads();
    }
    if (t < NBG) part[t] = sa[t] - pv;               // global exclusive
}

__global__ __launch_bounds__(256) void fill_k(
    const int* __restrict__ e, int* __restrict__ rp, const int* __restrict__ part,
    int* __restrict__ csr, const int* __restrict__ rank, int useRank,
    const int* __restrict__ flags)
{
    fill4_body(blockIdx.x, threadIdx.x, e, rp, part, csr, rank, flags[1], useRank);
}

// ---- gath: gather+mean. Front blocks: count rider. SPLIT=S col-slices with
//      XCD affinity under blockIdx%8 RR. r13 lesson: slice must stay >=128B
//      (one cache line) or misses fetch 2x useful bytes (SPLIT=8 @K=256 = 64B
//      slices -> FETCH 149->192MB, dur 78->96 REGRESSION). Respecting that:
//      K=256 -> SPLIT=4 (128B), K=128 -> SPLIT=2 (128B).
template<int K, int OSTR, int ROWS, int SPLIT>
__global__ __launch_bounds__(256) void gath(
    const unsigned short* __restrict__ hin,   // [N,K] bf16 (stride K)
    const int* __restrict__ rp, const int* __restrict__ part,
    const int* __restrict__ csr_src,
    unsigned short* __restrict__ mout,
    const int* __restrict__ eN, int* __restrict__ rpN,
    int* __restrict__ rankN, int useRank,
    const int* __restrict__ flags)
{
    constexpr int CH = K / 8;                 // 8-col chunks per row
    constexpr int CHS = CH / SPLIT;           // chunks this block owns
    static_assert(ROWS * CHS == 256, "one work item per thread");
    static_assert(CHS * 16 >= 128, "slice must cover a full 128B cache line");
    constexpr int NL = 8 / SPLIT;             // grid lanes per col-slice
    constexpr int CAP = 64 * ROWS;            // sidx capacity (4x mean degree)
    constexpr int NT = (N_NODES + ROWS - 1) / ROWS;
    __shared__ int sidx[CAP];
    __shared__ int srp[ROWS + 1];
    const int tid = threadIdx.x;
    if (blockIdx.x < EG4) {                   // count rider (front-loaded)
        count4_body(blockIdx.x, tid, eN, rpN, rankN, flags[1], useRank);
        return;
    }
    const int gb = (int)blockIdx.x - EG4;
    int m0, chBase;
    if (SPLIT == 1) {
        m0 = gb * ROWS; chBase = 0;
    } else {
        const int q = gb >> 3, r = gb & 7;
        const int tile = q * NL + (r & (NL - 1));
        if (tile >= NT) return;
        m0 = tile * ROWS;
        chBase = (r / NL) * CHS;              // XCD-affine under %8 RR
    }
    if (tid < ROWS + 1) srp[tid] = srp_load(m0, tid, rp, part, useRank);
    __syncthreads();
    const int base = srp[0];
    const int total = srp[ROWS] - base;
    const bool staged = total <= CAP;
    if (staged) {
        for (int i = tid; i < total; i += 256) sidx[i] = csr_src[base + i];
    }
    __syncthreads();

    {
        const int rr = tid / CHS;
        const int cc = tid & (CHS - 1);
        const int beg = srp[rr];
        const int deg = srp[rr + 1] - beg;
        const int begl = beg - base;
        float a[8], g[8];
#pragma unroll
        for (int v = 0; v < 8; ++v) { a[v] = 0.f; g[v] = 0.f; }
        const unsigned short* col = hin + (chBase + cc) * 8;
        if (staged) {
            auto IDX = [&](int j) { return sidx[begl + j]; };
            GATHER_RUN(IDX)
        } else {
            auto IDX = [&](int j) { return csr_src[beg + j]; };
            GATHER_RUN(IDX)
        }
        const float inv = 1.0f / fmaxf((float)deg, 1.0f);
        short8 t8;
#pragma unroll
        for (int v = 0; v < 8; ++v) t8[v] = (short)f2bfbits((a[v] + g[v]) * inv);
        if (m0 + rr < N_NODES)
            *(short8*)(mout + (size_t)(m0 + rr) * OSTR + (chBase + cc) * 8) = t8;
    }
}

// ---- gemmcat: M=64 GEMM over concat A=[mean|self], WcatT[n][2K]; fill rider FIRST ----
template<int K>
__global__ __launch_bounds__(256) void gemmcat(
    const unsigned short* __restrict__ mean, int mstr,
    const unsigned short* __restrict__ self, int sstr,
    const unsigned short* __restrict__ WcatT, // [256][2K]
    const unsigned short* __restrict__ bb,
    unsigned short* __restrict__ hout,        // [N,256]
    const int* __restrict__ ef, int* __restrict__ rpf, const int* __restrict__ partf,
    int* __restrict__ csr, const int* __restrict__ rank, int useRank,
    const int* __restrict__ flags)
{
    constexpr int KE = 2 * K;
    constexpr int KH = 128;                   // staged K-slice
    constexpr int NKH = KE / KH;              // 2 (K=128) or 4 (K=256)
    constexpr int LDA = KH + 8;
    __shared__ unsigned short A[64][LDA];     // 17.4 KB
    const int tid = threadIdx.x;
    if (blockIdx.x < EG4) {                   // fill rider (front-loaded, atomic-free)
        fill4_body(blockIdx.x, tid, ef, rpf, partf, csr, rank, flags[1], useRank);
        return;
    }
    const int m0 = (blockIdx.x - EG4) * 64;
    const int lane = tid & 63, wave = tid >> 6;
    const int r = lane & 15, quad = lane >> 4;

    floatx4 acc[4][4] = {};                   // [nti][mt], static-indexed only

#pragma unroll
    for (int kh = 0; kh < NKH; ++kh) {
        if (kh) __syncthreads();              // LDS reuse: readers of prev slice done
        for (int i = tid; i < 64 * (KH / 8); i += 256) {
            const int row = i / (KH / 8);
            const int c8 = i - row * (KH / 8);
            int grow = m0 + row; if (grow >= N_NODES) grow = N_NODES - 1;
            const int gc = kh * KH + c8 * 8;  // concat column
            const unsigned short* src = (gc < K)
                ? (mean + (size_t)grow * mstr + gc)
                : (self + (size_t)grow * sstr + (gc - K));
            *(uint4*)&A[row][c8 * 8] = *(const uint4*)src;
        }
        __syncthreads();
#pragma unroll
        for (int nti = 0; nti < 4; ++nti) {
            const int n0 = (wave + nti * 4) * 16;
            short8 bf[KH / 32];               // 4 x 16B weight frags
            const unsigned short* bp = WcatT + (size_t)(n0 + r) * KE + kh * KH + quad * 8;
#pragma unroll
            for (int k0 = 0; k0 < KH / 32; ++k0) bf[k0] = *(const short8*)(bp + k0 * 32);
#pragma unroll
            for (int mt = 0; mt < 4; ++mt) {
#pragma unroll
                for (int k0 = 0; k0 < KH / 32; ++k0)
                    acc[nti][mt] = __builtin_amdgcn_mfma_f32_16x16x32_bf16(
                        *(const short8*)&A[mt * 16 + r][k0 * 32 + quad * 8],
                        bf[k0], acc[nti][mt], 0, 0, 0);
            }
        }
    }

    // epilogue: C/D layout col = lane&15, row = quad*4 + reg  [HW-verified]
#pragma unroll
    for (int nti = 0; nti < 4; ++nti) {
        const int ccol = (wave + nti * 4) * 16 + r;
        const float bv = bfbits2f(bb[ccol]);
#pragma unroll
        for (int mt = 0; mt < 4; ++mt) {
#pragma unroll
            for (int i = 0; i < 4; ++i) {
                const int row = m0 + mt * 16 + quad * 4 + i;
                float v = acc[nti][mt][i] + bv;
                v = v > 0.f ? v : 0.f;
                if (row < N_NODES) hout[(size_t)row * 256 + ccol] = f2bfbits(v);
            }
        }
    }
}

// ---- L2 GEMM pair (stacked-N weights), M=64, no rider ----
__global__ __launch_bounds__(256) void gemmL2(
    const unsigned short* __restrict__ A,
    const unsigned short* __restrict__ WT,    // stacked-N [256][256]
    unsigned short* __restrict__ out0,
    unsigned short* __restrict__ out1)
{
    __shared__ unsigned short As[64][264];
    const int tid = threadIdx.x;
    const int m0 = blockIdx.x * 64;
    for (int i = tid; i < 64 * 32; i += 256) {
        int rr = i >> 5, cc = i & 31;
        int row = m0 + rr; if (row >= N_NODES) row = N_NODES - 1;
        *(uint4*)&As[rr][cc * 8] = *(const uint4*)(A + (size_t)row * 256 + cc * 8);
    }
    __syncthreads();
    const int lane = tid & 63, wave = tid >> 6;
    const int r = lane & 15, quad = lane >> 4;

    for (int nt = wave; nt < 16; nt += 4) {
        const int n0 = nt * 16;
        short8 bf[8];
        const unsigned short* bp = WT + (size_t)(n0 + r) * 256 + quad * 8;
#pragma unroll
        for (int k0 = 0; k0 < 8; ++k0) bf[k0] = *(const short8*)(bp + k0 * 32);
        const int ccol = n0 + r;
#pragma unroll
        for (int mt = 0; mt < 4; ++mt) {
            floatx4 acc = {0.f, 0.f, 0.f, 0.f};
#pragma unroll
            for (int k0 = 0; k0 < 8; ++k0)
                acc = __builtin_amdgcn_mfma_f32_16x16x32_bf16(
                    *(const short8*)&As[mt * 16 + r][k0 * 32 + quad * 8], bf[k0], acc, 0, 0, 0);
#pragma unroll
            for (int i = 0; i < 4; ++i) {
                const int row = m0 + mt * 16 + quad * 4 + i;
                if (row < N_NODES) {
                    unsigned short v = f2bfbits(acc[i]);
                    if (ccol < 128) out0[(size_t)row * 128 + ccol] = v;
                    else            out1[(size_t)row * 128 + ccol - 128] = v;
                }
            }
        }
    }
}

// ---- L2 aggregate + epilogue, SPLIT=2 (r12-proven: 32 rows x 8 chunks x 2
//      XCD-affine halves; 128B slices — r13's SPLIT=4 64B slices regressed) ----
__global__ __launch_bounds__(256) void agg2(
    const unsigned short* __restrict__ hl2,
    const unsigned short* __restrict__ hr2,
    const int* __restrict__ rp, const int* __restrict__ part,
    const int* __restrict__ csr_src,
    const unsigned short* __restrict__ bb,
    void* __restrict__ out, int useRank,
    const int* __restrict__ flags)
{
    constexpr int K = 128, CAP = 3072;
    constexpr int ROWS = 32, CHS = 8;         // 32*8 = 256 work items
    constexpr int NT = (N_NODES + ROWS - 1) / ROWS;   // 1563
    __shared__ int sidx[CAP];
    __shared__ int srp[ROWS + 1];
    const int tid = threadIdx.x;
    const int gb = blockIdx.x;
    const int q = gb >> 3, r8 = gb & 7;
    const int tile = q * 4 + (r8 & 3);
    if (tile >= NT) return;
    const int m0 = tile * ROWS;
    const int chBase = (r8 >> 2) * CHS;
    if (tid < ROWS + 1) srp[tid] = srp_load(m0, tid, rp, part, useRank);
    __syncthreads();
    const int base = srp[0];
    const int total = srp[ROWS] - base;
    const bool staged = total <= CAP;
    if (staged) {
        for (int i = tid; i < total; i += 256) sidx[i] = csr_src[base + i];
    }
    __syncthreads();

    const int rr = tid >> 3;                  // 0..31
    const int cc = tid & 7;                   // 0..7
    const int beg = srp[rr];
    const int deg = srp[rr + 1] - beg;
    const int begl = beg - base;
    float a[8], g[8];
#pragma unroll
    for (int v = 0; v < 8; ++v) { a[v] = 0.f; g[v] = 0.f; }
    const unsigned short* col = hl2 + (chBase + cc) * 8;
    if (staged) {
        auto IDX = [&](int j) { return sidx[begl + j]; };
        GATHER_RUN(IDX)
    } else {
        auto IDX = [&](int j) { return csr_src[beg + j]; };
        GATHER_RUN(IDX)
    }

    const float inv = 1.0f / fmaxf((float)deg, 1.0f);
    const int row = m0 + rr;
    const int rowc = (row < N_NODES) ? row : N_NODES - 1;
    const size_t ro = (size_t)rowc * K + (chBase + cc) * 8;
    uint4 hv = *(const uint4*)(hr2 + ro);
    uint4 bv = *(const uint4*)(bb + (chBase + cc) * 8);
    float h8[8], b8[8];
    h8[0] = bfbits2f(hv.x & 0xffffu); h8[1] = bfbits2f(hv.x >> 16);
    h8[2] = bfbits2f(hv.y & 0xffffu); h8[3] = bfbits2f(hv.y >> 16);
    h8[4] = bfbits2f(hv.z & 0xffffu); h8[5] = bfbits2f(hv.z >> 16);
    h8[6] = bfbits2f(hv.w & 0xffffu); h8[7] = bfbits2f(hv.w >> 16);
    b8[0] = bfbits2f(bv.x & 0xffffu); b8[1] = bfbits2f(bv.x >> 16);
    b8[2] = bfbits2f(bv.y & 0xffffu); b8[3] = bfbits2f(bv.y >> 16);
    b8[4] = bfbits2f(bv.z & 0xffffu); b8[5] = bfbits2f(bv.z >> 16);
    b8[6] = bfbits2f(bv.w & 0xffffu); b8[7] = bfbits2f(bv.w >> 16);
    float o8[8];
#pragma unroll
    for (int v = 0; v < 8; ++v) {
        float m = (a[v] + g[v]) * inv + b8[v] + h8[v];
        o8[v] = m > 0.f ? m : 0.f;
    }
    if (row >= N_NODES) return;
    if (flags[0]) {
        float* op = (float*)out + ro;
        float4 o0 = { o8[0], o8[1], o8[2], o8[3] };
        float4 o1 = { o8[4], o8[5], o8[6], o8[7] };
        *(float4*)op = o0;
        *(float4*)(op + 4) = o1;
    } else {
        short8 t8;
#pragma unroll
        for (int v = 0; v < 8; ++v) t8[v] = (short)f2bfbits(o8[v]);
        *(short8*)((unsigned short*)out + ro) = t8;
    }
}

// ---------------- orchestration ----------------
extern "C" void kernel_launch(void* const* d_in, const int* in_sizes, int n_in,
                              void* d_out, int out_size, void* d_ws, size_t ws_size,
                              hipStream_t stream) {
    const void* x  = d_in[0];
    const int* e[3] = { (const int*)d_in[1], (const int*)d_in[2], (const int*)d_in[3] };

    char* ws = (char*)d_ws;
    int* flags = (int*)ws;                                    // @0
    unsigned short* wt = (unsigned short*)(ws + 1024);        // 525,568 B -> 526,592
    unsigned short* bb0 = wt + 262144;
    unsigned short* bb1 = wt + 262400;
    unsigned short* bb2 = wt + 262656;
    int* rp3    = (int*)(ws + 526592);                        // 150,000 ints -> 1,126,592
    int* ticket = (int*)(ws + 1126592);                       // 3 ints -> 1,126,604
    int* part3  = (int*)(ws + 1126604);                       // 3*196 ints -> 1,128,956
    int* csr    = (int*)(ws + 1128960);                       // 3.2 MB -> 4,328,960
    unsigned short* hA = (unsigned short*)(ws + 4328960);     // 25.6 MB -> 29,928,960
    unsigned short* hB = (unsigned short*)(ws + 29928960);    // 25.6 MB -> 55,528,960
    int* rank  = (int*)(ws + 55528960);                       // 3.2 MB -> 58,728,960 (guarded)
    unsigned short* xb  = hB;                 // overlay: dies when gath1 writes hB (xb dead after gemm0)
    unsigned short* hl2 = hA;                 // overlay: hA dead after gemm1 reads it (self)
    unsigned short* hr2 = hA + (size_t)N_NODES * 128;

    const int useRank = (ws_size >= (size_t)58728960) ? 1 : 0;  // fallback = legacy cursor fill

    int* rp0 = rp3, * rp1 = rp3 + N_NODES, * rp2 = rp3 + 2 * N_NODES;
    int* pt0 = part3, * pt1 = part3 + NBG, * pt2 = part3 + 2 * NBG;

    // 1) zero counters + tickets (contiguous)
    hipMemsetAsync(rp3, 0, 600012, stream);
    // 2) prep + cvt + count graph0 (count0 FRONT-LOADED; writes rank when useRank)
    mega1<<<8060, 256, 0, stream>>>(d_in[4], d_in[6], d_in[7], d_in[9],
                                    d_in[10], d_in[12], d_in[5], d_in[8], d_in[11],
                                    wt, x, xb, e[0], rp0, rank, useRank, flags);
    // 3) scan graph0
    scan_g<<<NBG, 256, 0, stream>>>(rp0, pt0, ticket + 0);
    // 4) fill graph0 (atomic-free when useRank)
    fill_k<<<EG4, 256, 0, stream>>>(e[0], rp0, pt0, csr, rank, useRank, flags);
    // 5) gather0 SPLIT=2 (r12-proven, 128B slices): mean(xb) -> hA; rider: count graph1
    gath<128, 256, 32, 2><<<EG4 + G128S2, 256, 0, stream>>>(xb, rp0, pt0, csr, hA,
                                                            e[1], rp1, rank, useRank, flags);
    // 6) scan graph1 (tiny)
    scan_g<<<NBG, 256, 0, stream>>>(rp1, pt1, ticket + 1);
    // 7) L0 GEMM in-place on hA; front rider: fill graph1 (csr free after gath0)
    gemmcat<128><<<EG4 + MG64, 256, 0, stream>>>(hA, 256, xb, 128,
                                                 wt, bb0, hA,
                                                 e[1], rp1, pt1, csr, rank, useRank, flags);
    // 8) gather1 SPLIT=4 (mid-point: 128B slices, 6.4MB/XCD): mean(hA) -> hB; rider: count graph2
    gath<256, 256, 32, 4><<<EG4 + G256S4, 256, 0, stream>>>(hA, rp1, pt1, csr, hB,
                                                            e[2], rp2, rank, useRank, flags);
    // 9) scan graph2 (tiny)
    scan_g<<<NBG, 256, 0, stream>>>(rp2, pt2, ticket + 2);
    // 10) L1 GEMM in-place on hB (mean=hB, self=hA); front rider: fill graph2
    gemmcat<256><<<EG4 + MG64, 256, 0, stream>>>(hB, 256, hA, 256,
                                                 wt + 65536, bb1, hB,
                                                 e[2], rp2, pt2, csr, rank, useRank, flags);
    // 11) L2 GEMM pair (M=64)
    gemmL2<<<MG64, 256, 0, stream>>>(hB, wt + 196608, hl2, hr2);
    // 12) L2 aggregate + epilogue SPLIT=2 -> d_out
    agg2<<<AGG2G, 256, 0, stream>>>(hl2, hr2, rp2, pt2, csr, bb2, d_out, useRank, flags);
}